// Round 1
// baseline (356.482 us; speedup 1.0000x reference)
//
#include <hip/hip_runtime.h>
#include <stdint.h>

#define NB 2
#define NN 100
#define HWP (800*1344)        // 1,075,200 pixels per image
#define GCH 10                // instances per chunk
#define NCH 10                // ceil(NN/GCH)
#define NKEY (1<<(GCH+1))     // 2048 histogram bins (claimed bit + 10 chunk bits)
#define NSEM 134
#define IGN 133
#define PXT 16                // pixels per thread
#define THR 256
#define PXB (PXT*THR)         // 4096 pixels per block
#define NBLK ((HWP + PXB - 1)/PXB)   // 263

// ---------- init owner = 0xFF ----------
__global__ void init_owner_kernel(uint8_t* owner) {
    const size_t n = (size_t)NB * HWP / 16;
    size_t i = (size_t)blockIdx.x * blockDim.x + threadIdx.x;
    uint4 v = make_uint4(0xFFFFFFFFu, 0xFFFFFFFFu, 0xFFFFFFFFu, 0xFFFFFFFFu);
    for (; i < n; i += (size_t)gridDim.x * blockDim.x)
        ((uint4*)owner)[i] = v;
}

// ---------- stable descending sort of candidates (score >= 0.5), zero small bufs ----------
__global__ void sort_kernel(const float* __restrict__ scores, const int* __restrict__ cls,
                            int* order, float* score_s, int* cls_s, int* iid_s,
                            unsigned* hist, unsigned* counts, unsigned* keptcnt,
                            unsigned* Mcnt, unsigned* flag) {
    __shared__ float ss[NB * NN];
    int t = threadIdx.x;
    for (int i = t; i < NB * NKEY; i += THR) hist[i] = 0;
    for (int i = t; i < NB * NSEM; i += THR) counts[i] = 0;
    if (t < NB) { keptcnt[t] = 0; Mcnt[t] = 0; }
    if (t == 0) *flag = 0;
    for (int i = t; i < NB * NN; i += THR) { ss[i] = scores[i]; iid_s[i] = 0; }
    __syncthreads();
    for (int idx = t; idx < NB * NN; idx += THR) {
        int b = idx / NN, i = idx % NN;
        float s = ss[b * NN + i];
        if (s >= 0.5f) {   // only candidates can ever be kept; others are no-ops
            int r = 0;
            for (int j = 0; j < NN; ++j) {
                float sj = ss[b * NN + j];
                if (sj >= 0.5f && (sj > s || (sj == s && j < i))) r++;
            }
            order[b * NN + r]   = i;
            score_s[b * NN + r] = s;
            cls_s[b * NN + r]   = cls[b * NN + i];
            atomicAdd(&Mcnt[b], 1u);
        }
    }
}

// ---------- detect whether masks are u8 bools (flag=1) or int32 0/1 (flag=0) ----------
__global__ void detect_kernel(const unsigned* __restrict__ masks, unsigned* flag) {
    int t = threadIdx.x;
    unsigned any = 0;
    for (int i = t; i < 16384; i += THR)
        any |= (masks[i] > 1u) ? 1u : 0u;
    if (any) atomicOr(flag, 1u);
}

// ---------- per-chunk histogram over (claimed, chunk-membership) keys ----------
__global__ __launch_bounds__(THR) void hist_kernel(
        const void* __restrict__ masks, const int* __restrict__ order,
        const unsigned* __restrict__ Mcnt, const unsigned* __restrict__ flag,
        const uint8_t* __restrict__ owner, uint16_t* __restrict__ cbits,
        unsigned* __restrict__ hist, int chunk) {
    int b = blockIdx.y;
    int L = (int)Mcnt[b] - chunk * GCH;
    if (L <= 0) return;
    if (L > GCH) L = GCH;
    __shared__ unsigned lh[NKEY];
    __shared__ int midx[GCH];
    int t = threadIdx.x;
    for (int i = t; i < NKEY; i += THR) lh[i] = 0;
    if (t < L) midx[t] = order[b * NN + chunk * GCH + t];
    __syncthreads();
    const int mode_u8 = (int)(*flag);
    long p0 = ((long)blockIdx.x * THR + t) * PXT;
    if (p0 < HWP) {
        unsigned keys[PXT];
        if (chunk == 0) {
            #pragma unroll
            for (int k = 0; k < PXT; ++k) keys[k] = 0;
        } else {
            uint4 ov = *(const uint4*)(owner + (size_t)b * HWP + p0);
            unsigned w[4] = {ov.x, ov.y, ov.z, ov.w};
            #pragma unroll
            for (int k = 0; k < PXT; ++k) {
                unsigned by = (w[k >> 2] >> ((k & 3) * 8)) & 0xFFu;
                keys[k] = (by != 0xFFu) ? (1u << GCH) : 0u;
            }
        }
        for (int g = 0; g < L; ++g) {
            size_t base = ((size_t)b * NN + midx[g]) * HWP + (size_t)p0;
            unsigned bits16;
            if (mode_u8) {
                uint4 v = *(const uint4*)((const uint8_t*)masks + base);
                unsigned n0 = (((v.x & 0x01010101u) * 0x01020408u) >> 24) & 0xFu;
                unsigned n1 = (((v.y & 0x01010101u) * 0x01020408u) >> 24) & 0xFu;
                unsigned n2 = (((v.z & 0x01010101u) * 0x01020408u) >> 24) & 0xFu;
                unsigned n3 = (((v.w & 0x01010101u) * 0x01020408u) >> 24) & 0xFu;
                bits16 = n0 | (n1 << 4) | (n2 << 8) | (n3 << 12);
            } else {
                const uint4* mp = (const uint4*)((const int*)masks + base);
                bits16 = 0;
                #pragma unroll
                for (int q = 0; q < 4; ++q) {
                    uint4 v = mp[q];
                    bits16 |= ((v.x & 1u) | ((v.y & 1u) << 1) | ((v.z & 1u) << 2) |
                               ((v.w & 1u) << 3)) << (q * 4);
                }
            }
            #pragma unroll
            for (int k = 0; k < PXT; ++k) keys[k] |= ((bits16 >> k) & 1u) << g;
        }
        // store chunk membership bits (claimed bit harmless: kchunk < 2^GCH)
        uint4 c0, c1;
        c0.x = keys[0] | (keys[1] << 16);  c0.y = keys[2]  | (keys[3] << 16);
        c0.z = keys[4] | (keys[5] << 16);  c0.w = keys[6]  | (keys[7] << 16);
        c1.x = keys[8] | (keys[9] << 16);  c1.y = keys[10] | (keys[11] << 16);
        c1.z = keys[12] | (keys[13] << 16); c1.w = keys[14] | (keys[15] << 16);
        uint4* cbp = (uint4*)(cbits + (size_t)b * HWP + p0);
        cbp[0] = c0; cbp[1] = c1;
        #pragma unroll
        for (int k = 0; k < PXT; ++k) atomicAdd(&lh[keys[k]], 1u);
    }
    __syncthreads();
    for (int i = t; i < NKEY; i += THR) {
        unsigned v = lh[i];
        if (v) atomicAdd(&hist[b * NKEY + i], v);
    }
}

// ---------- resolve keep decisions for a chunk from the histogram ----------
__global__ void resolve_kernel(const float* __restrict__ score_s,
                               const unsigned* __restrict__ Mcnt,
                               unsigned* hist, int* iid_s, unsigned* kchunk,
                               unsigned* keptcnt, int chunk) {
    int t = threadIdx.x;
    if (t < 64) {  // wave 0 does sequential logic, lane-parallel over bins
        for (int b = 0; b < NB; ++b) {
            int L = (int)Mcnt[b] - chunk * GCH;
            if (L > GCH) L = GCH;
            unsigned kmask = 0;
            unsigned kc = keptcnt[b];
            for (int g = 0; g < L; ++g) {
                unsigned lowm = (1u << g) - 1u;
                unsigned area = 0, inter = 0;
                for (int i = t; i < NKEY; i += 64) {
                    unsigned h = hist[b * NKEY + i];
                    unsigned ui = (unsigned)i;
                    if (h && ((ui >> g) & 1u)) {
                        area += h;
                        if ((ui >> GCH) | (ui & kmask & lowm)) inter += h;
                    }
                }
                #pragma unroll
                for (int off = 32; off > 0; off >>= 1) {
                    area  += __shfl_xor(area, off);
                    inter += __shfl_xor(inter, off);
                }
                float s = score_s[b * NN + chunk * GCH + g];
                // inter <= 0.5f*area (both exact in f32, area < 2^24) == 2*inter <= area
                bool keep = (s >= 0.5f) && (area > 0u) && (2u * inter <= area);
                if (keep) {
                    kmask |= (1u << g);
                    kc += 1;
                    if (t == 0) iid_s[b * NN + chunk * GCH + g] = (int)kc;
                }
            }
            if (t == 0) { kchunk[chunk * NB + b] = kmask; keptcnt[b] = kc; }
        }
    }
    __syncthreads();
    for (int i = t; i < NB * NKEY; i += blockDim.x) hist[i] = 0;  // ready for next chunk
}

// ---------- apply kept instances of a chunk to owner map ----------
__global__ __launch_bounds__(THR) void apply_kernel(
        const unsigned* __restrict__ kchunk, const uint16_t* __restrict__ cbits,
        uint8_t* __restrict__ owner, int chunk) {
    int b = blockIdx.y;
    unsigned km = kchunk[chunk * NB + b];
    if (!km) return;
    int t = threadIdx.x;
    long p0 = ((long)blockIdx.x * THR + t) * PXT;
    if (p0 >= HWP) return;
    uint4* op = (uint4*)(owner + (size_t)b * HWP + p0);
    uint4 ov = *op;
    const uint4* cbp = (const uint4*)(cbits + (size_t)b * HWP + p0);
    uint4 c0 = cbp[0], c1 = cbp[1];
    unsigned cw[8] = {c0.x, c0.y, c0.z, c0.w, c1.x, c1.y, c1.z, c1.w};
    unsigned w[4] = {ov.x, ov.y, ov.z, ov.w};
    bool changed = false;
    #pragma unroll
    for (int k = 0; k < PXT; ++k) {
        unsigned by = (w[k >> 2] >> ((k & 3) * 8)) & 0xFFu;
        if (by == 0xFFu) {
            unsigned bits = (cw[k >> 1] >> ((k & 1) * 16)) & ((1u << GCH) - 1u);
            unsigned hit = bits & km;
            if (hit) {
                unsigned nb = (unsigned)(chunk * GCH + __builtin_ctz(hit));
                w[k >> 2] = (w[k >> 2] & ~(0xFFu << ((k & 3) * 8))) | (nb << ((k & 3) * 8));
                changed = true;
            }
        }
    }
    if (changed) { ov.x = w[0]; ov.y = w[1]; ov.z = w[2]; ov.w = w[3]; *op = ov; }
}

// ---------- stuff area counts over unclaimed pixels ----------
__global__ __launch_bounds__(THR) void count_kernel(
        const int* __restrict__ sem, const uint8_t* __restrict__ owner,
        unsigned* __restrict__ counts) {
    int b = blockIdx.y;
    __shared__ unsigned lh[NSEM];
    int t = threadIdx.x;
    for (int i = t; i < NSEM; i += THR) lh[i] = 0;
    __syncthreads();
    long p0 = ((long)blockIdx.x * THR + t) * PXT;
    if (p0 < HWP) {
        uint4 ov = *(const uint4*)(owner + (size_t)b * HWP + p0);
        unsigned w[4] = {ov.x, ov.y, ov.z, ov.w};
        const uint4* sp = (const uint4*)(sem + (size_t)b * HWP + p0);
        #pragma unroll
        for (int q = 0; q < 4; ++q) {
            uint4 sv = sp[q];
            unsigned sarr[4] = {sv.x, sv.y, sv.z, sv.w};
            #pragma unroll
            for (int j = 0; j < 4; ++j) {
                int k = q * 4 + j;
                unsigned by = (w[k >> 2] >> ((k & 3) * 8)) & 0xFFu;
                if (by == 0xFFu) {
                    unsigned c = sarr[j];
                    if (c != (unsigned)IGN) atomicAdd(&lh[c], 1u);
                }
            }
        }
    }
    __syncthreads();
    for (int i = t; i < NSEM; i += THR) {
        unsigned v = lh[i];
        if (v) atomicAdd(&counts[b * NSEM + i], v);
    }
}

// ---------- final pan write (things + stuff fusion) ----------
__global__ __launch_bounds__(THR) void writepan_kernel(
        const int* __restrict__ sem, const uint8_t* __restrict__ owner,
        const unsigned* __restrict__ counts, const int* __restrict__ cls_s,
        const int* __restrict__ iid_s, int* __restrict__ out) {
    int b = blockIdx.y;
    __shared__ int pval[NN];
    __shared__ int sval[NSEM];
    int t = threadIdx.x;
    for (int i = t; i < NN; i += THR) pval[i] = cls_s[b * NN + i] + iid_s[b * NN + i] * 1000;
    for (int i = t; i < NSEM; i += THR)
        sval[i] = (i != IGN && counts[b * NSEM + i] >= 4096u) ? (i + 80) : 0;
    __syncthreads();
    long p0 = ((long)blockIdx.x * THR + t) * PXT;
    if (p0 >= HWP) return;
    uint4 ov = *(const uint4*)(owner + (size_t)b * HWP + p0);
    unsigned w[4] = {ov.x, ov.y, ov.z, ov.w};
    const uint4* sp = (const uint4*)(sem + (size_t)b * HWP + p0);
    int4* op = (int4*)(out + (size_t)b * HWP + p0);
    #pragma unroll
    for (int q = 0; q < 4; ++q) {
        uint4 sv = sp[q];
        unsigned sarr[4] = {sv.x, sv.y, sv.z, sv.w};
        int res[4];
        #pragma unroll
        for (int j = 0; j < 4; ++j) {
            int k = q * 4 + j;
            unsigned by = (w[k >> 2] >> ((k & 3) * 8)) & 0xFFu;
            res[j] = (by != 0xFFu) ? pval[by] : sval[sarr[j]];
        }
        op[q] = make_int4(res[0], res[1], res[2], res[3]);
    }
}

extern "C" void kernel_launch(void* const* d_in, const int* in_sizes, int n_in,
                              void* d_out, int out_size, void* d_ws, size_t ws_size,
                              hipStream_t stream) {
    const void*  masks  = d_in[0];                 // bool masks: u8 or i32 (auto-detected)
    const float* scores = (const float*)d_in[1];
    const int*   cls    = (const int*)d_in[2];
    const int*   sem    = (const int*)d_in[3];
    int* out = (int*)d_out;

    uint8_t* base = (uint8_t*)d_ws;
    uint8_t*  owner  = base;                    base += (size_t)NB * HWP;       // 2,150,400
    uint16_t* cbits  = (uint16_t*)base;         base += (size_t)NB * HWP * 2;   // 4,300,800
    unsigned* hist   = (unsigned*)base;         base += (size_t)NB * NKEY * 4;
    unsigned* counts = (unsigned*)base;         base += (size_t)NB * NSEM * 4;
    int*      order  = (int*)base;              base += (size_t)NB * NN * 4;
    float*    score_s= (float*)base;            base += (size_t)NB * NN * 4;
    int*      cls_s  = (int*)base;              base += (size_t)NB * NN * 4;
    int*      iid_s  = (int*)base;              base += (size_t)NB * NN * 4;
    unsigned* kchunk = (unsigned*)base;         base += (size_t)NCH * NB * 4;
    unsigned* keptcnt= (unsigned*)base;         base += (size_t)NB * 4;
    unsigned* Mcnt   = (unsigned*)base;         base += (size_t)NB * 4;
    unsigned* flag   = (unsigned*)base;         base += 4;

    dim3 g2(NBLK, NB);
    hipLaunchKernelGGL(init_owner_kernel, dim3(525), dim3(THR), 0, stream, owner);
    hipLaunchKernelGGL(sort_kernel, dim3(1), dim3(THR), 0, stream,
                       scores, cls, order, score_s, cls_s, iid_s,
                       hist, counts, keptcnt, Mcnt, flag);
    hipLaunchKernelGGL(detect_kernel, dim3(1), dim3(THR), 0, stream,
                       (const unsigned*)masks, flag);
    for (int c = 0; c < NCH; ++c) {
        hipLaunchKernelGGL(hist_kernel, g2, dim3(THR), 0, stream,
                           masks, order, Mcnt, flag, owner, cbits, hist, c);
        hipLaunchKernelGGL(resolve_kernel, dim3(1), dim3(THR), 0, stream,
                           score_s, Mcnt, hist, iid_s, kchunk, keptcnt, c);
        hipLaunchKernelGGL(apply_kernel, g2, dim3(THR), 0, stream,
                           kchunk, cbits, owner, c);
    }
    hipLaunchKernelGGL(count_kernel, g2, dim3(THR), 0, stream, sem, owner, counts);
    hipLaunchKernelGGL(writepan_kernel, g2, dim3(THR), 0, stream,
                       sem, owner, counts, cls_s, iid_s, out);
}